// Round 7
// baseline (2462.803 us; speedup 1.0000x reference)
//
#include <hip/hip_runtime.h>
#include <hip/hip_fp16.h>
#include <stdint.h>

#define B_TOTAL 1024
#define T_TOTAL 1024
#define LOG2E 1.44269504088896f

typedef _Float16 f16x2 __attribute__((ext_vector_type(2)));

__device__ __forceinline__ float dot2w(uint32_t xw, uint32_t ww, float acc) {
#if __has_builtin(__builtin_amdgcn_fdot2)
    return __builtin_amdgcn_fdot2(__builtin_bit_cast(f16x2, xw),
                                  __builtin_bit_cast(f16x2, ww), acc, false);
#else
    f16x2 xv = __builtin_bit_cast(f16x2, xw);
    f16x2 wv = __builtin_bit_cast(f16x2, ww);
    return acc + (float)xv.x * (float)wv.x + (float)xv.y * (float)wv.y;
#endif
}

__device__ __forceinline__ uint32_t packf2(float a, float b) {
    f16x2 t;
    t.x = (_Float16)a;
    t.y = (_Float16)b;
    return __builtin_bit_cast(uint32_t, t);
}

__device__ __forceinline__ float sigm_(float z) {
    float e = __builtin_amdgcn_exp2f(-LOG2E * z);
    return __builtin_amdgcn_rcpf(1.0f + e);
}
__device__ __forceinline__ float tanh_(float z) {
    float e = __builtin_amdgcn_exp2f((2.0f * LOG2E) * z);
    float r = __builtin_amdgcn_rcpf(1.0f + e);
    return __builtin_fmaf(-2.0f, r, 1.0f);
}

__device__ __forceinline__ void wavebar() {
#if __has_builtin(__builtin_amdgcn_wave_barrier)
    __builtin_amdgcn_wave_barrier();
#endif
}

// ====================== projection pass (round 7) ======================
// r6 counters: L2 proj 83us vs ~19us HBM bound — inner loop did one
// ds_read_b32 of wt per fdot2 (100 LDS ops/tile). Fix: one-time copy of
// each thread's OPT output columns into REGISTERS (wreg[NDW][OPT], all
// indices compile-time); inner loop = b128 xin reads + pure fdot2.
// Row order/addressing identical to r6 (correctness-validated).
template <int DIN, int H, int NDIR, bool L1X>
__global__ void __launch_bounds__(256) proj_kernel(
    const float* __restrict__ x,        // L1X: [B][T][8] f32
    const __half* __restrict__ inbuf,   // else: [T][B][DIN] f16
    const float* __restrict__ w0,       // W_ih fwd [4H][DIN] f32
    const float* __restrict__ w1,       // W_ih bwd
    __half* __restrict__ g0,            // Gx fwd [seglen*B][4H] f16
    __half* __restrict__ g1,            // Gx bwd
    int t0, int seglen)
{
    constexpr int NDW  = DIN / 2;          // input dwords (f16 pairs)
    constexpr int XPAD = (NDW + 3) & ~3;   // xin row pad (b128 alignment)
    constexpr int O4H  = 4 * H;
    constexpr int ODW  = O4H / 2;
    constexpr int RPB  = 16;               // rows per tile
    constexpr int TPR  = 16;               // threads per row
    constexpr int OPT  = (O4H + TPR - 1) / TPR;
    constexpr int TILES = 8;

    __shared__ uint32_t wt[NDW][O4H];
    __shared__ uint32_t xin[RPB * XPAD];
    __shared__ uint32_t osm[RPB][ODW];

    const int tid  = threadIdx.x;
    const int dirz = (NDIR == 2) ? (int)blockIdx.y : 0;
    const float* w = dirz ? w1 : w0;
    __half* gout   = dirz ? g1 : g0;
    (void)seglen;

    // stage W^T once: wt[d][o], o = j*4 + q (scan reads 4 gates as one b64)
    for (int idx = tid; idx < NDW * O4H; idx += 256) {
        const int d  = idx / O4H;
        const int o  = idx - d * O4H;
        const int jj = o >> 2;
        const int qq = o & 3;
        wt[d][o] = packf2(w[(qq * H + jj) * DIN + 2 * d],
                          w[(qq * H + jj) * DIN + 2 * d + 1]);
    }
    __syncthreads();

    const int rr = tid >> 4;   // row within tile
    const int li = tid & 15;   // thread within row

    // one-time: this thread's OPT columns -> registers (static indices)
    uint32_t wreg[NDW][OPT];
#pragma unroll
    for (int d = 0; d < NDW; ++d)
#pragma unroll
        for (int oi = 0; oi < OPT; ++oi) {
            const int o = li + oi * TPR;
            wreg[d][oi] = (O4H % TPR == 0 || o < O4H) ? wt[d][o] : 0u;
        }

    for (int tile = 0; tile < TILES; ++tile) {
        const int r0 = ((int)blockIdx.x * TILES + tile) * RPB;
        __syncthreads();   // prev tile's xin/osm consumers done

        // ---- load 16 input rows ----
        for (int idx = tid; idx < RPB * NDW; idx += 256) {
            const int rl = idx / NDW;
            const int d  = idx - rl * NDW;
            const int r  = r0 + rl;
            const int i  = r >> 10;               // B_TOTAL = 1024
            const int bb = r & (B_TOTAL - 1);
            const int t  = dirz ? (T_TOTAL - 1 - t0 - i) : (t0 + i);
            uint32_t v;
            if constexpr (L1X) {
                float2 u = {0.f, 0.f};
                if (d < 4)
                    u = ((const float2*)(x + ((size_t)bb * T_TOTAL + t) * 8))[d];
                else if (t > 0)
                    u = ((const float2*)(x + ((size_t)bb * T_TOTAL + (t - 1)) * 8))[d - 4];
                v = packf2(u.x, u.y);
            } else {
                v = ((const uint32_t*)inbuf)[((size_t)t * B_TOTAL + bb) * NDW + d];
            }
            xin[rl * XPAD + d] = v;
        }
        __syncthreads();

        // ---- dots: b128 xin + register weights ----
        float acc[OPT];
#pragma unroll
        for (int oi = 0; oi < OPT; ++oi) acc[oi] = 0.f;
        const uint32_t* xr = &xin[rr * XPAD];
#pragma unroll
        for (int d = 0; d + 4 <= NDW; d += 4) {
            const uint4 xv = *(const uint4*)(xr + d);
#pragma unroll
            for (int oi = 0; oi < OPT; ++oi) {
                acc[oi] = dot2w(xv.x, wreg[d][oi], acc[oi]);
                acc[oi] = dot2w(xv.y, wreg[d + 1][oi], acc[oi]);
                acc[oi] = dot2w(xv.z, wreg[d + 2][oi], acc[oi]);
                acc[oi] = dot2w(xv.w, wreg[d + 3][oi], acc[oi]);
            }
        }
        if constexpr ((NDW & 3) >= 2) {
            constexpr int d0 = NDW & ~3;
            const uint2 xv = *(const uint2*)(xr + d0);
#pragma unroll
            for (int oi = 0; oi < OPT; ++oi) {
                acc[oi] = dot2w(xv.x, wreg[d0][oi], acc[oi]);
                acc[oi] = dot2w(xv.y, wreg[d0 + 1][oi], acc[oi]);
            }
        }
        {
            __half* oh = (__half*)&osm[rr][0];
#pragma unroll
            for (int oi = 0; oi < OPT; ++oi) {
                const int o = li + oi * TPR;
                if (O4H % TPR == 0 || o < O4H) oh[o] = __float2half(acc[oi]);
            }
        }
        __syncthreads();   // osm ready

        // ---- coalesced flush ----
        {
            uint32_t* dst = (uint32_t*)gout;
            for (int idx = tid; idx < RPB * ODW; idx += 256) {
                const int r  = idx / ODW;
                const int od = idx - r * ODW;
                dst[(size_t)(r0 + r) * ODW + od] = osm[r][od];
            }
        }
    }
}

// ================= lean scan pass, 2-way interleave (round 7) =================
// r6 scan was ~560 cy/step: the ds_write(h) -> ds_read(hd) round trip (~2x
// ~120cy DS latency, m117) sat naked on the serial chain every step. Fix:
// each wave carries TWO independent batch recurrences (slot A = batches
// [blk*NB, +GPW), slot B = [+GPW, +2*GPW)), same t. Per iteration:
//   readB | computeA+writeA | readA | computeB+writeB
// Each slot's write->read gap AND read latency is covered by the other
// slot's ~200cy compute. Per-wave DS ops complete in order, so
// write-before-read in program order needs no barrier (wavebar = compiler
// fence only). W_hh pinned in VGPRs via opaque asm (r0-r3 remat lesson).
template <int H, bool STORE_ALL>
__global__ void __launch_bounds__(64)
__attribute__((amdgpu_waves_per_eu(1, 1))) lstm_scan2(
    const __half* __restrict__ gxf, const __half* __restrict__ gxb,
    const float* __restrict__ whhf, const float* __restrict__ bihf,
    const float* __restrict__ bhhf,
    const float* __restrict__ whhb, const float* __restrict__ bihb,
    const float* __restrict__ bhhb,
    __half* __restrict__ outbuf,    // STORE_ALL: [T][B][2H] f16
    float* __restrict__ lasth,      // !STORE_ALL: [B][H] f32
    float* __restrict__ sth, float* __restrict__ stc,  // [2][B][H] f32 state
    int t0, int seglen)
{
    constexpr int GPW   = 64 / H;     // spatial groups per wave
    constexpr int NB    = 2 * GPW;    // batches per block (2 time-slots)
    constexpr int NH    = H / 2;
    constexpr int HS_DW = (H == 20) ? 12 : 8;
    constexpr int PFD   = 4;          // prefetch depth per slot

    const int dir  = blockIdx.y;
    const int lane = threadIdx.x;
    const int g    = lane / H;
    const int j    = lane - g * H;
    const int bA   = blockIdx.x * NB + g;
    const int bB   = blockIdx.x * NB + GPW + g;
    const bool vA  = (g < GPW) && (bA < B_TOTAL);
    const bool vB  = (g < GPW) && (bB < B_TOTAL);
    const int bsA  = vA ? bA : (B_TOTAL - 1);
    const int bsB  = vB ? bB : (B_TOTAL - 1);

    const __half* gx  = dir ? gxb : gxf;
    const float* w_hh = dir ? whhb : whhf;
    const float* b_i  = dir ? bihb : bihf;
    const float* b_h  = dir ? bhhb : bhhf;

    __shared__ uint32_t hsm[2][GPW + 1][HS_DW];

    uint32_t whh2[4][NH];
    float bias[4];
#pragma unroll
    for (int q = 0; q < 4; ++q) {
        const int r = q * H + j;
#pragma unroll
        for (int k = 0; k < NH; ++k)
            whh2[q][k] = packf2(w_hh[r * H + 2 * k], w_hh[r * H + 2 * k + 1]);
        bias[q] = b_i[r] + b_h[r];
    }
#pragma unroll
    for (int q = 0; q < 4; ++q) {
#pragma unroll
        for (int k = 0; k < NH; ++k) asm volatile("" : "+v"(whh2[q][k]));
        asm volatile("" : "+v"(bias[q]));
    }

    // ---- state (zeros at t0==0, else persisted) ----
    float cA, h0A, cB, h0B;
    if (t0 == 0) {
        cA = h0A = cB = h0B = 0.f;
    } else {
        h0A = sth[((size_t)dir * B_TOTAL + bsA) * H + j];
        cA  = stc[((size_t)dir * B_TOTAL + bsA) * H + j];
        h0B = sth[((size_t)dir * B_TOTAL + bsB) * H + j];
        cB  = stc[((size_t)dir * B_TOTAL + bsB) * H + j];
    }
    ((__half*)&hsm[0][g][0])[j] = __float2half(h0A);
    ((__half*)&hsm[1][g][0])[j] = __float2half(h0B);
    wavebar();

    uint32_t hdA[NH], hdB[NH];

#define READHD(hd, S)                                                         \
    {                                                                         \
        const uint32_t* hp = &hsm[S][g][0];                                   \
        if constexpr (NH == 10) {                                             \
            uint4 v0 = *(const uint4*)hp;                                     \
            uint4 v1 = *(const uint4*)(hp + 4);                               \
            uint2 v2 = *(const uint2*)(hp + 8);                               \
            hd[0] = v0.x; hd[1] = v0.y; hd[2] = v0.z; hd[3] = v0.w;           \
            hd[4] = v1.x; hd[5] = v1.y; hd[6] = v1.z; hd[7] = v1.w;           \
            hd[8] = v2.x; hd[9] = v2.y;                                       \
        } else {                                                              \
            uint4 v0 = *(const uint4*)hp;                                     \
            hd[0] = v0.x; hd[1] = v0.y; hd[2] = v0.z; hd[3] = v0.w;           \
            hd[4] = hp[4];                                                    \
        }                                                                     \
    }

    READHD(hdA, 0)   // hdB read at loop top (covered by phase A)

    // ---- Gx prefetch rings ----
    const size_t ISTR = (size_t)B_TOTAL * (4 * H) * 2;
    const char* gbA = (const char*)gx + ((size_t)bsA * (4 * H) + (size_t)j * 4) * 2;
    const char* gbB = (const char*)gx + ((size_t)bsB * (4 * H) + (size_t)j * 4) * 2;

    uint2 pfA[PFD], pfB[PFD];
#pragma unroll
    for (int i2 = 0; i2 < PFD; ++i2) {
        const int ip = (i2 < seglen) ? i2 : (seglen - 1);
        pfA[i2] = *(const uint2*)(gbA + (size_t)ip * ISTR);
        pfB[i2] = *(const uint2*)(gbB + (size_t)ip * ISTR);
    }

    __half *opA = nullptr, *opB = nullptr;
    ptrdiff_t opstep = 0;
    if constexpr (STORE_ALL) {
        const int tstart = dir ? (T_TOTAL - 1 - t0) : t0;
        opA = outbuf + (size_t)tstart * (B_TOTAL * 2 * H) + (size_t)bsA * (2 * H) + dir * H + j;
        opB = outbuf + (size_t)tstart * (B_TOTAL * 2 * H) + (size_t)bsB * (2 * H) + dir * H + j;
        opstep = (dir ? -1 : 1) * (ptrdiff_t)(B_TOTAL * 2 * H);
    }

    float hlA = h0A, hlB = h0B;

#define PHASE(hd, pfr, gbp, cst, opp, hl, VV, S, I)                           \
    {                                                                         \
        const uint2 gv = pfr[I];                                              \
        int ip = sb + (I) + PFD;                                              \
        ip = (ip < seglen) ? ip : (seglen - 1);                               \
        pfr[I] = *(const uint2*)(gbp + (size_t)ip * ISTR);                    \
        const f16x2 p01 = __builtin_bit_cast(f16x2, gv.x);                    \
        const f16x2 p23 = __builtin_bit_cast(f16x2, gv.y);                    \
        float a0 = (float)p01.x + bias[0];                                    \
        float a1 = (float)p01.y + bias[1];                                    \
        float a2 = (float)p23.x + bias[2];                                    \
        float a3 = (float)p23.y + bias[3];                                    \
        _Pragma("unroll")                                                     \
        for (int k = 0; k < NH; ++k) {                                        \
            a0 = dot2w(hd[k], whh2[0][k], a0);                                \
            a1 = dot2w(hd[k], whh2[1][k], a1);                                \
            a2 = dot2w(hd[k], whh2[2][k], a2);                                \
            a3 = dot2w(hd[k], whh2[3][k], a3);                                \
        }                                                                     \
        const float iv  = sigm_(a0);                                          \
        const float fv  = sigm_(a1);                                          \
        const float gg2 = tanh_(a2);                                          \
        const float ov  = sigm_(a3);                                          \
        cst = __builtin_fmaf(fv, cst, iv * gg2);                              \
        const float hh = ov * tanh_(cst);                                     \
        ((__half*)&hsm[S][g][0])[j] = __float2half(hh);                       \
        hl = hh;                                                              \
        if constexpr (STORE_ALL) {                                            \
            if (VV) *opp = __float2half(hh);                                  \
            opp += opstep;                                                    \
        }                                                                     \
    }

#define ITER(I)                                                               \
    wavebar();                                                                \
    READHD(hdB, 1)                                                            \
    PHASE(hdA, pfA, gbA, cA, opA, hlA, vA, 0, I)                              \
    wavebar();                                                                \
    READHD(hdA, 0)                                                            \
    PHASE(hdB, pfB, gbB, cB, opB, hlB, vB, 1, I)

    for (int sb = 0; sb < seglen; sb += PFD) {
        ITER(0) ITER(1) ITER(2) ITER(3)
    }
#undef ITER
#undef PHASE
#undef READHD

    if (vA) {
        sth[((size_t)dir * B_TOTAL + bA) * H + j] = hlA;
        stc[((size_t)dir * B_TOTAL + bA) * H + j] = cA;
        if constexpr (!STORE_ALL) lasth[bA * H + j] = hlA;
    }
    if (vB) {
        sth[((size_t)dir * B_TOTAL + bB) * H + j] = hlB;
        stc[((size_t)dir * B_TOTAL + bB) * H + j] = cB;
        if constexpr (!STORE_ALL) lasth[bB * H + j] = hlB;
    }
}

// L4 backward needed only at t=T-1 (single step from zero state) + FC + sigmoid.
__global__ void final_kernel(const __half* __restrict__ l3out,  // [T][B][20] f16
                             const float* __restrict__ hf4,     // [B][10]
                             const float* __restrict__ w_ih,    // w4b_ih [40][20]
                             const float* __restrict__ b_ih,
                             const float* __restrict__ b_hh,
                             const float* __restrict__ fc_w,    // [20]
                             const float* __restrict__ fc_b,
                             float* __restrict__ out)           // [B]
{
    const int b = blockIdx.x * blockDim.x + threadIdx.x;
    if (b >= B_TOTAL) return;

    float in4[20];
    const __half* p = l3out + (size_t)(T_TOTAL - 1) * (B_TOTAL * 20) + (size_t)b * 20;
#pragma unroll
    for (int i = 0; i < 20; ++i) in4[i] = __half2float(p[i]);

    float z = fc_b[0];
#pragma unroll
    for (int k = 0; k < 10; ++k) z += fc_w[k] * hf4[b * 10 + k];

#pragma unroll
    for (int k = 0; k < 10; ++k) {
        float gi = b_ih[k]      + b_hh[k];
        float gg = b_ih[20 + k] + b_hh[20 + k];
        float go = b_ih[30 + k] + b_hh[30 + k];
#pragma unroll
        for (int i = 0; i < 20; ++i) {
            const float xi = in4[i];
            gi += w_ih[k * 20 + i]        * xi;
            gg += w_ih[(20 + k) * 20 + i] * xi;
            go += w_ih[(30 + k) * 20 + i] * xi;
        }
        const float cc = sigm_(gi) * tanh_(gg);
        const float hb = sigm_(go) * tanh_(cc);
        z += fc_w[10 + k] * hb;
    }
    out[b] = sigm_(z);
}

extern "C" void kernel_launch(void* const* d_in, const int* in_sizes, int n_in,
                              void* d_out, int out_size, void* d_ws, size_t ws_size,
                              hipStream_t stream) {
    const float* x = (const float*)d_in[0];
    auto W = [&](int li, int dr, int k) -> const float* {
        return (const float*)d_in[1 + (li - 1) * 8 + dr * 4 + k];
    };
    const float* fc_w = (const float*)d_in[33];
    const float* fc_b = (const float*)d_in[34];
    float* out = (float*)d_out;

    // ---- workspace layout (identical to r6, correctness-validated) ----
    const size_t HA_B = (size_t)T_TOTAL * B_TOTAL * 40 * 2;
    const size_t HB_B = (size_t)T_TOTAL * B_TOTAL * 20 * 2;
    const size_t ST_B = 2ull * B_TOTAL * 20 * 4;
    const size_t F4_B = (size_t)B_TOTAL * 10 * 4;

    char* p = (char*)d_ws;
    __half* hA = (__half*)p;  p += HA_B;
    __half* hB = (__half*)p;  p += HB_B;
    float* sth = (float*)p;   p += ST_B;
    float* stc = (float*)p;   p += ST_B;
    float* hf4 = (float*)p;   p += F4_B;
    __half* gx = (__half*)p;

    const size_t base = HA_B + HB_B + 2 * ST_B + F4_B;
    int SEG = 64;
    if      (ws_size >= base + 1024ull * 327680) SEG = 1024;
    else if (ws_size >= base +  512ull * 327680) SEG = 512;
    else if (ws_size >= base +  256ull * 327680) SEG = 256;
    else if (ws_size >= base +  128ull * 327680) SEG = 128;
    const int nseg = T_TOTAL / SEG;

    auto g1of = [&](int H) { return gx + (size_t)SEG * 1024 * 4 * H; };

    // ---- L1: DIN=16 (x + lag), H=20 -> hA ----
    for (int s = 0; s < nseg; ++s) {
        proj_kernel<16, 20, 2, true><<<dim3(SEG * 8, 2), 256, 0, stream>>>(
            x, nullptr, W(1,0,0), W(1,1,0), gx, g1of(20), s * SEG, SEG);
        lstm_scan2<20, true><<<dim3(171, 2), 64, 0, stream>>>(
            gx, g1of(20), W(1,0,1), W(1,0,2), W(1,0,3),
                          W(1,1,1), W(1,1,2), W(1,1,3),
            hA, nullptr, sth, stc, s * SEG, SEG);
    }
    // ---- L2: DIN=40, H=20, hA -> hA (in-place; proj(s) precedes scan(s)) ----
    for (int s = 0; s < nseg; ++s) {
        proj_kernel<40, 20, 2, false><<<dim3(SEG * 8, 2), 256, 0, stream>>>(
            nullptr, hA, W(2,0,0), W(2,1,0), gx, g1of(20), s * SEG, SEG);
        lstm_scan2<20, true><<<dim3(171, 2), 64, 0, stream>>>(
            gx, g1of(20), W(2,0,1), W(2,0,2), W(2,0,3),
                          W(2,1,1), W(2,1,2), W(2,1,3),
            hA, nullptr, sth, stc, s * SEG, SEG);
    }
    // ---- L3: DIN=40, H=10, hA -> hB ----
    for (int s = 0; s < nseg; ++s) {
        proj_kernel<40, 10, 2, false><<<dim3(SEG * 8, 2), 256, 0, stream>>>(
            nullptr, hA, W(3,0,0), W(3,1,0), gx, g1of(10), s * SEG, SEG);
        lstm_scan2<10, true><<<dim3(86, 2), 64, 0, stream>>>(
            gx, g1of(10), W(3,0,1), W(3,0,2), W(3,0,3),
                          W(3,1,1), W(3,1,2), W(3,1,3),
            hB, nullptr, sth, stc, s * SEG, SEG);
    }
    // ---- L4 forward only: DIN=20, H=10, hB -> hf4 ----
    for (int s = 0; s < nseg; ++s) {
        proj_kernel<20, 10, 1, false><<<dim3(SEG * 8, 1), 256, 0, stream>>>(
            nullptr, hB, W(4,0,0), W(4,0,0), gx, gx, s * SEG, SEG);
        lstm_scan2<10, false><<<dim3(86, 1), 64, 0, stream>>>(
            gx, gx, W(4,0,1), W(4,0,2), W(4,0,3),
                    W(4,0,1), W(4,0,2), W(4,0,3),
            nullptr, hf4, sth, stc, s * SEG, SEG);
    }

    final_kernel<<<dim3(4), 256, 0, stream>>>(
        hB, hf4, W(4,1,0), W(4,1,2), W(4,1,3), fc_w, fc_b, out);
}

// Round 9
// 2114.482 us; speedup vs baseline: 1.1647x; 1.1647x over previous
//
#include <hip/hip_runtime.h>
#include <hip/hip_fp16.h>
#include <stdint.h>

#define B_TOTAL 1024
#define T_TOTAL 1024
#define LOG2E 1.44269504088896f

typedef _Float16 f16x2 __attribute__((ext_vector_type(2)));

__device__ __forceinline__ float dot2w(uint32_t xw, uint32_t ww, float acc) {
#if __has_builtin(__builtin_amdgcn_fdot2)
    return __builtin_amdgcn_fdot2(__builtin_bit_cast(f16x2, xw),
                                  __builtin_bit_cast(f16x2, ww), acc, false);
#else
    f16x2 xv = __builtin_bit_cast(f16x2, xw);
    f16x2 wv = __builtin_bit_cast(f16x2, ww);
    return acc + (float)xv.x * (float)wv.x + (float)xv.y * (float)wv.y;
#endif
}

__device__ __forceinline__ uint32_t packf2(float a, float b) {
    f16x2 t;
    t.x = (_Float16)a;
    t.y = (_Float16)b;
    return __builtin_bit_cast(uint32_t, t);
}

__device__ __forceinline__ float sigm_(float z) {
    float e = __builtin_amdgcn_exp2f(-LOG2E * z);
    return __builtin_amdgcn_rcpf(1.0f + e);
}
__device__ __forceinline__ float tanh_(float z) {
    float e = __builtin_amdgcn_exp2f((2.0f * LOG2E) * z);
    float r = __builtin_amdgcn_rcpf(1.0f + e);
    return __builtin_fmaf(-2.0f, r, 1.0f);
}

__device__ __forceinline__ void wavebar() {
#if __has_builtin(__builtin_amdgcn_wave_barrier)
    __builtin_amdgcn_wave_barrier();
#endif
}

// ====================== projection pass (unchanged, r7-validated) ======================
template <int DIN, int H, int NDIR, bool L1X>
__global__ void __launch_bounds__(256) proj_kernel(
    const float* __restrict__ x,        // L1X: [B][T][8] f32
    const __half* __restrict__ inbuf,   // else: [T][B][DIN] f16
    const float* __restrict__ w0,       // W_ih fwd [4H][DIN] f32
    const float* __restrict__ w1,       // W_ih bwd
    __half* __restrict__ g0,            // Gx fwd [seglen*B][4H] f16
    __half* __restrict__ g1,            // Gx bwd
    int t0, int seglen)
{
    constexpr int NDW  = DIN / 2;
    constexpr int XPAD = (NDW + 3) & ~3;
    constexpr int O4H  = 4 * H;
    constexpr int ODW  = O4H / 2;
    constexpr int RPB  = 16;
    constexpr int TPR  = 16;
    constexpr int OPT  = (O4H + TPR - 1) / TPR;
    constexpr int TILES = 8;

    __shared__ __align__(16) uint32_t wt[NDW][O4H];
    __shared__ __align__(16) uint32_t xin[RPB * XPAD];
    __shared__ __align__(16) uint32_t osm[RPB][ODW];

    const int tid  = threadIdx.x;
    const int dirz = (NDIR == 2) ? (int)blockIdx.y : 0;
    const float* w = dirz ? w1 : w0;
    __half* gout   = dirz ? g1 : g0;
    (void)seglen;

    for (int idx = tid; idx < NDW * O4H; idx += 256) {
        const int d  = idx / O4H;
        const int o  = idx - d * O4H;
        const int jj = o >> 2;
        const int qq = o & 3;
        wt[d][o] = packf2(w[(qq * H + jj) * DIN + 2 * d],
                          w[(qq * H + jj) * DIN + 2 * d + 1]);
    }
    __syncthreads();

    const int rr = tid >> 4;
    const int li = tid & 15;

    uint32_t wreg[NDW][OPT];
#pragma unroll
    for (int d = 0; d < NDW; ++d)
#pragma unroll
        for (int oi = 0; oi < OPT; ++oi) {
            const int o = li + oi * TPR;
            wreg[d][oi] = (O4H % TPR == 0 || o < O4H) ? wt[d][o] : 0u;
        }

    for (int tile = 0; tile < TILES; ++tile) {
        const int r0 = ((int)blockIdx.x * TILES + tile) * RPB;
        __syncthreads();

        for (int idx = tid; idx < RPB * NDW; idx += 256) {
            const int rl = idx / NDW;
            const int d  = idx - rl * NDW;
            const int r  = r0 + rl;
            const int i  = r >> 10;
            const int bb = r & (B_TOTAL - 1);
            const int t  = dirz ? (T_TOTAL - 1 - t0 - i) : (t0 + i);
            uint32_t v;
            if constexpr (L1X) {
                float2 u = {0.f, 0.f};
                if (d < 4)
                    u = ((const float2*)(x + ((size_t)bb * T_TOTAL + t) * 8))[d];
                else if (t > 0)
                    u = ((const float2*)(x + ((size_t)bb * T_TOTAL + (t - 1)) * 8))[d - 4];
                v = packf2(u.x, u.y);
            } else {
                v = ((const uint32_t*)inbuf)[((size_t)t * B_TOTAL + bb) * NDW + d];
            }
            xin[rl * XPAD + d] = v;
        }
        __syncthreads();

        float acc[OPT];
#pragma unroll
        for (int oi = 0; oi < OPT; ++oi) acc[oi] = 0.f;
        const uint32_t* xr = &xin[rr * XPAD];
#pragma unroll
        for (int d = 0; d + 4 <= NDW; d += 4) {
            const uint4 xv = *(const uint4*)(xr + d);
#pragma unroll
            for (int oi = 0; oi < OPT; ++oi) {
                acc[oi] = dot2w(xv.x, wreg[d][oi], acc[oi]);
                acc[oi] = dot2w(xv.y, wreg[d + 1][oi], acc[oi]);
                acc[oi] = dot2w(xv.z, wreg[d + 2][oi], acc[oi]);
                acc[oi] = dot2w(xv.w, wreg[d + 3][oi], acc[oi]);
            }
        }
        if constexpr ((NDW & 3) >= 2) {
            constexpr int d0 = NDW & ~3;
            const uint2 xv = *(const uint2*)(xr + d0);
#pragma unroll
            for (int oi = 0; oi < OPT; ++oi) {
                acc[oi] = dot2w(xv.x, wreg[d0][oi], acc[oi]);
                acc[oi] = dot2w(xv.y, wreg[d0 + 1][oi], acc[oi]);
            }
        }
        {
            __half* oh = (__half*)&osm[rr][0];
#pragma unroll
            for (int oi = 0; oi < OPT; ++oi) {
                const int o = li + oi * TPR;
                if (O4H % TPR == 0 || o < O4H) oh[o] = __float2half(acc[oi]);
            }
        }
        __syncthreads();

        {
            uint32_t* dst = (uint32_t*)gout;
            for (int idx = tid; idx < RPB * ODW; idx += 256) {
                const int r  = idx / ODW;
                const int od = idx - r * ODW;
                dst[(size_t)(r0 + r) * ODW + od] = osm[r][od];
            }
        }
    }
}

// ================== staged-feed lean scan (round 9 = r8 + LDS align fix) ==================
// r7 evidence: register-ring 8B/step trickle loads are feed-limited
// (22KB in flight chip-wide -> ~650GB/s demand ceiling = the 121us).
// Fix = r4's proven chunk staging: 16 steps of Gx staged into
// double-buffered LDS with dwordx4 loads (2.6MB in flight chip-wide),
// per-step gx = one ds_read_b64 prefetched 1 step ahead.
// h broadcast + h output unified in hout[16][row]: one b16 write/step
// serves next-step hd read AND a batched dword-store flush per 16 steps.
// r8 container failure audit: gxs lacked __align__(16) but is accessed
// via b128/b64 DS ops -> potential misaligned-DS fault. Fixed here.
template <int H, bool STORE_ALL>
__global__ void __launch_bounds__(64)
__attribute__((amdgpu_waves_per_eu(1, 1))) lstm_scan3(
    const __half* __restrict__ gxf, const __half* __restrict__ gxb,
    const float* __restrict__ whhf, const float* __restrict__ bihf,
    const float* __restrict__ bhhf,
    const float* __restrict__ whhb, const float* __restrict__ bihb,
    const float* __restrict__ bhhb,
    __half* __restrict__ outbuf,    // STORE_ALL: [T][B][2H] f16
    float* __restrict__ lasth,      // !STORE_ALL: [B][H] f32
    float* __restrict__ sth, float* __restrict__ stc,  // [2][B][H] f32 state
    int t0, int seglen)             // seglen multiple of 16 (>= 64)
{
    constexpr int GPW   = 64 / H;          // 3 (H=20) or 6 (H=10)
    constexpr int NH    = H / 2;
    constexpr int PADH  = (H == 20) ? 24 : 12;   // hout per-group half stride
    constexpr int B8H   = 8 * H;           // bytes per batch in a gx row
    constexpr int SLICE = GPW * B8H;       // block's bytes per row = 480 both H

    const int dir  = blockIdx.y;
    const int lane = threadIdx.x;
    const int g    = lane / H;
    const int j    = lane - g * H;
    const int gs   = (g < GPW) ? g : (GPW - 1);
    const int b    = blockIdx.x * GPW + g;
    const bool valid = (g < GPW) && (b < B_TOTAL);
    const int bs   = valid ? b : (B_TOTAL - 1);

    const __half* gx  = dir ? gxb : gxf;
    const float* w_hh = dir ? whhb : whhf;
    const float* b_i  = dir ? bihb : bihf;
    const float* b_h  = dir ? bhhb : bhhf;

    __shared__ __align__(16) uint32_t gxs[2][16 * 120];   // 2 x 7680B
    __shared__ __align__(16) __half hout[16][80];         // 16 rows x 160B

    // ---- W_hh + bias -> registers, pinned ----
    uint32_t whh2[4][NH];
    float bias[4];
#pragma unroll
    for (int q = 0; q < 4; ++q) {
        const int r = q * H + j;
#pragma unroll
        for (int k = 0; k < NH; ++k)
            whh2[q][k] = packf2(w_hh[r * H + 2 * k], w_hh[r * H + 2 * k + 1]);
        bias[q] = b_i[r] + b_h[r];
    }
#pragma unroll
    for (int q = 0; q < 4; ++q) {
#pragma unroll
        for (int k = 0; k < NH; ++k) asm volatile("" : "+v"(whh2[q][k]));
        asm volatile("" : "+v"(bias[q]));
    }

    // ---- staging machinery ----
    const size_t ISTR = (size_t)B_TOTAL * B8H;           // gx row bytes
    const uint32_t boff = (uint32_t)blockIdx.x * SLICE;
    const uint32_t SL = (uint32_t)(((size_t)boff + SLICE <= ISTR) ? SLICE
                                                                  : (ISTR - boff));
    const int sub = lane >> 5, l32 = lane & 31;
    const uint32_t loff = (uint32_t)l32 * 16;
    const uint32_t offc = (loff < SL) ? loff : 0u;       // clamped, in-bounds
    const char* gxc = (const char*)gx;

    uint4 greg[8];
    auto issue_loads = [&](int cbase) {
#pragma unroll
        for (int r = 0; r < 8; ++r) {
            const int i = 2 * r + sub;
            greg[r] = *(const uint4*)(gxc + (size_t)(cbase + i) * ISTR + boff + offc);
        }
    };
    auto write_stage = [&](int bb) {
        if (loff < SL) {
#pragma unroll
            for (int r = 0; r < 8; ++r) {
                const int i = 2 * r + sub;
                *(uint4*)((char*)&gxs[bb][0] + (size_t)i * 480 + loff) = greg[r];
            }
        }
    };

    // ---- h broadcast read ----
    uint32_t hd[NH];
    auto read_hd = [&](int row) {
        const char* hp = (const char*)&hout[0][0] + row * 160 + gs * (PADH * 2);
        if constexpr (H == 20) {
            uint4 v0 = *(const uint4*)hp;
            uint4 v1 = *(const uint4*)(hp + 16);
            uint2 v2 = *(const uint2*)(hp + 32);
            hd[0] = v0.x; hd[1] = v0.y; hd[2] = v0.z; hd[3] = v0.w;
            hd[4] = v1.x; hd[5] = v1.y; hd[6] = v1.z; hd[7] = v1.w;
            hd[8] = v2.x; hd[9] = v2.y;
        } else {
            uint2 v0 = *(const uint2*)hp;
            uint2 v1 = *(const uint2*)(hp + 8);
            hd[0] = v0.x; hd[1] = v0.y; hd[2] = v1.x; hd[3] = v1.y;
            hd[4] = *(const uint32_t*)(hp + 16);
        }
    };
    // write slot: g>=GPW lanes redirected to scratch halfs [72,80)
    const int hoff = (g < GPW) ? (gs * PADH + j) : (72 + (lane & 7));

    // ---- state ----
    float c_st, h0;
    if (t0 == 0) {
        c_st = 0.f;
        h0   = 0.f;
    } else {
        h0   = sth[((size_t)dir * B_TOTAL + bs) * H + j];
        c_st = stc[((size_t)dir * B_TOTAL + bs) * H + j];
    }
    *(__half*)((char*)&hout[0][0] + 15 * 160 + hoff * 2) = __float2half(h0);
    wavebar();
    read_hd(15);

    // ---- prime chunks 0 and 1 ----
    issue_loads(0);
    write_stage(0);          // vmcnt wait folded here (once per dispatch)
    issue_loads(16);
    wavebar();

    const int gxrd = gs * (2 * H) + j * 2;    // dword offset in a staged row
    uint2 gxcur = *(const uint2*)((const char*)&gxs[0][0] + gxrd * 4);
    uint2 gxn;

    float hl = h0;

    auto step = [&](int i, int cur) {
        // prefetch next step's gx (row i+1; at i==15 row 0 of other buffer)
        const int nrow = (i < 15) ? (i + 1) : 0;
        const int nbuf = (i < 15) ? cur : (cur ^ 1);
        gxn = *(const uint2*)((const char*)&gxs[nbuf][0] + nrow * 480 + gxrd * 4);

        const f16x2 p01 = __builtin_bit_cast(f16x2, gxcur.x);
        const f16x2 p23 = __builtin_bit_cast(f16x2, gxcur.y);
        float a0 = (float)p01.x + bias[0];
        float a1 = (float)p01.y + bias[1];
        float a2 = (float)p23.x + bias[2];
        float a3 = (float)p23.y + bias[3];
        float e0 = 0.f, e1 = 0.f, e2 = 0.f, e3 = 0.f;
#pragma unroll
        for (int k = 0; k < NH / 2; ++k) {
            a0 = dot2w(hd[k], whh2[0][k], a0);
            a1 = dot2w(hd[k], whh2[1][k], a1);
            a2 = dot2w(hd[k], whh2[2][k], a2);
            a3 = dot2w(hd[k], whh2[3][k], a3);
        }
#pragma unroll
        for (int k = NH / 2; k < NH; ++k) {
            e0 = dot2w(hd[k], whh2[0][k], e0);
            e1 = dot2w(hd[k], whh2[1][k], e1);
            e2 = dot2w(hd[k], whh2[2][k], e2);
            e3 = dot2w(hd[k], whh2[3][k], e3);
        }
        a0 += e0; a1 += e1; a2 += e2; a3 += e3;

        const float iv  = sigm_(a0);
        const float fv  = sigm_(a1);
        const float gg2 = tanh_(a2);
        const float ov  = sigm_(a3);
        c_st = __builtin_fmaf(fv, c_st, iv * gg2);
        const float h = ov * tanh_(c_st);

        *(__half*)((char*)&hout[0][0] + i * 160 + hoff * 2) = __float2half(h);
        wavebar();
        read_hd(i);          // next step's hd (in-order DS after the write)
        gxcur = gxn;
        hl = h;
    };

    auto flush = [&](int cb) {
        if constexpr (STORE_ALL) {
#pragma unroll
            for (int r = 0; r < 8; ++r) {
                const int fd = r * 64 + lane;
                if (fd < 480) {
                    const int t  = fd / 30;        // GPW*NH == 30 for both H
                    const int w  = fd - t * 30;
                    const int gg = w / NH;
                    const int kk = w - gg * NH;
                    const uint32_t hv = *(const uint32_t*)((const char*)&hout[0][0] +
                                          t * 160 + (gg * PADH + 2 * kk) * 2);
                    const int bb2 = blockIdx.x * GPW + gg;
                    if (bb2 < B_TOTAL) {
                        const int tg = dir ? (T_TOTAL - 1 - (t0 + cb + t))
                                           : (t0 + cb + t);
                        *(uint32_t*)((char*)outbuf +
                            ((size_t)tg * (B_TOTAL * 2 * H) +
                             (size_t)bb2 * (2 * H) + dir * H) * 2 + kk * 4) = hv;
                    }
                }
            }
        }
    };

    const int nch = seglen / 16;
    int cur = 0;
    for (int c = 0; c < nch; ++c) {
        const int cb = c * 16;
#pragma unroll
        for (int i = 0; i < 8; ++i) step(i, cur);
        if (c + 1 < nch) write_stage(cur ^ 1);     // chunk c+1 -> other buffer
#pragma unroll
        for (int i = 8; i < 16; ++i) step(i, cur);
        flush(cb);
        if (c + 2 < nch) issue_loads(cb + 32);     // chunk c+2 -> greg
        cur ^= 1;
    }

    if (valid) {
        sth[((size_t)dir * B_TOTAL + b) * H + j] = hl;
        stc[((size_t)dir * B_TOTAL + b) * H + j] = c_st;
        if constexpr (!STORE_ALL) lasth[b * H + j] = hl;
    }
}

// L4 backward needed only at t=T-1 (single step from zero state) + FC + sigmoid.
__global__ void final_kernel(const __half* __restrict__ l3out,  // [T][B][20] f16
                             const float* __restrict__ hf4,     // [B][10]
                             const float* __restrict__ w_ih,    // w4b_ih [40][20]
                             const float* __restrict__ b_ih,
                             const float* __restrict__ b_hh,
                             const float* __restrict__ fc_w,    // [20]
                             const float* __restrict__ fc_b,
                             float* __restrict__ out)           // [B]
{
    const int b = blockIdx.x * blockDim.x + threadIdx.x;
    if (b >= B_TOTAL) return;

    float in4[20];
    const __half* p = l3out + (size_t)(T_TOTAL - 1) * (B_TOTAL * 20) + (size_t)b * 20;
#pragma unroll
    for (int i = 0; i < 20; ++i) in4[i] = __half2float(p[i]);

    float z = fc_b[0];
#pragma unroll
    for (int k = 0; k < 10; ++k) z += fc_w[k] * hf4[b * 10 + k];

#pragma unroll
    for (int k = 0; k < 10; ++k) {
        float gi = b_ih[k]      + b_hh[k];
        float gg = b_ih[20 + k] + b_hh[20 + k];
        float go = b_ih[30 + k] + b_hh[30 + k];
#pragma unroll
        for (int i = 0; i < 20; ++i) {
            const float xi = in4[i];
            gi += w_ih[k * 20 + i]        * xi;
            gg += w_ih[(20 + k) * 20 + i] * xi;
            go += w_ih[(30 + k) * 20 + i] * xi;
        }
        const float cc = sigm_(gi) * tanh_(gg);
        const float hb = sigm_(go) * tanh_(cc);
        z += fc_w[10 + k] * hb;
    }
    out[b] = sigm_(z);
}

extern "C" void kernel_launch(void* const* d_in, const int* in_sizes, int n_in,
                              void* d_out, int out_size, void* d_ws, size_t ws_size,
                              hipStream_t stream) {
    const float* x = (const float*)d_in[0];
    auto W = [&](int li, int dr, int k) -> const float* {
        return (const float*)d_in[1 + (li - 1) * 8 + dr * 4 + k];
    };
    const float* fc_w = (const float*)d_in[33];
    const float* fc_b = (const float*)d_in[34];
    float* out = (float*)d_out;

    // ---- workspace layout (r6/r7-validated) ----
    const size_t HA_B = (size_t)T_TOTAL * B_TOTAL * 40 * 2;
    const size_t HB_B = (size_t)T_TOTAL * B_TOTAL * 20 * 2;
    const size_t ST_B = 2ull * B_TOTAL * 20 * 4;
    const size_t F4_B = (size_t)B_TOTAL * 10 * 4;

    char* p = (char*)d_ws;
    __half* hA = (__half*)p;  p += HA_B;
    __half* hB = (__half*)p;  p += HB_B;
    float* sth = (float*)p;   p += ST_B;
    float* stc = (float*)p;   p += ST_B;
    float* hf4 = (float*)p;   p += F4_B;
    __half* gx = (__half*)p;

    const size_t base = HA_B + HB_B + 2 * ST_B + F4_B;
    int SEG = 64;
    if      (ws_size >= base + 1024ull * 327680) SEG = 1024;
    else if (ws_size >= base +  512ull * 327680) SEG = 512;
    else if (ws_size >= base +  256ull * 327680) SEG = 256;
    else if (ws_size >= base +  128ull * 327680) SEG = 128;
    const int nseg = T_TOTAL / SEG;

    auto g1of = [&](int H) { return gx + (size_t)SEG * 1024 * 4 * H; };

    // ---- L1: DIN=16 (x + lag), H=20 -> hA ----
    for (int s = 0; s < nseg; ++s) {
        proj_kernel<16, 20, 2, true><<<dim3(SEG * 8, 2), 256, 0, stream>>>(
            x, nullptr, W(1,0,0), W(1,1,0), gx, g1of(20), s * SEG, SEG);
        lstm_scan3<20, true><<<dim3(342, 2), 64, 0, stream>>>(
            gx, g1of(20), W(1,0,1), W(1,0,2), W(1,0,3),
                          W(1,1,1), W(1,1,2), W(1,1,3),
            hA, nullptr, sth, stc, s * SEG, SEG);
    }
    // ---- L2: DIN=40, H=20, hA -> hA (in-place; proj(s) precedes scan(s)) ----
    for (int s = 0; s < nseg; ++s) {
        proj_kernel<40, 20, 2, false><<<dim3(SEG * 8, 2), 256, 0, stream>>>(
            nullptr, hA, W(2,0,0), W(2,1,0), gx, g1of(20), s * SEG, SEG);
        lstm_scan3<20, true><<<dim3(342, 2), 64, 0, stream>>>(
            gx, g1of(20), W(2,0,1), W(2,0,2), W(2,0,3),
                          W(2,1,1), W(2,1,2), W(2,1,3),
            hA, nullptr, sth, stc, s * SEG, SEG);
    }
    // ---- L3: DIN=40, H=10, hA -> hB ----
    for (int s = 0; s < nseg; ++s) {
        proj_kernel<40, 10, 2, false><<<dim3(SEG * 8, 2), 256, 0, stream>>>(
            nullptr, hA, W(3,0,0), W(3,1,0), gx, g1of(10), s * SEG, SEG);
        lstm_scan3<10, true><<<dim3(171, 2), 64, 0, stream>>>(
            gx, g1of(10), W(3,0,1), W(3,0,2), W(3,0,3),
                          W(3,1,1), W(3,1,2), W(3,1,3),
            hB, nullptr, sth, stc, s * SEG, SEG);
    }
    // ---- L4 forward only: DIN=20, H=10, hB -> hf4 ----
    for (int s = 0; s < nseg; ++s) {
        proj_kernel<20, 10, 1, false><<<dim3(SEG * 8, 1), 256, 0, stream>>>(
            nullptr, hB, W(4,0,0), W(4,0,0), gx, gx, s * SEG, SEG);
        lstm_scan3<10, false><<<dim3(171, 1), 64, 0, stream>>>(
            gx, gx, W(4,0,1), W(4,0,2), W(4,0,3),
                    W(4,0,1), W(4,0,2), W(4,0,3),
            nullptr, hf4, sth, stc, s * SEG, SEG);
    }

    final_kernel<<<dim3(4), 256, 0, stream>>>(
        hB, hf4, W(4,1,0), W(4,1,2), W(4,1,3), fc_w, fc_b, out);
}

// Round 10
// 1929.123 us; speedup vs baseline: 1.2766x; 1.0961x over previous
//
#include <hip/hip_runtime.h>
#include <hip/hip_fp16.h>
#include <stdint.h>

#define B_TOTAL 1024
#define T_TOTAL 1024
#define LOG2E 1.44269504088896f

typedef _Float16 f16x2 __attribute__((ext_vector_type(2)));

__device__ __forceinline__ float dot2w(uint32_t xw, uint32_t ww, float acc) {
#if __has_builtin(__builtin_amdgcn_fdot2)
    return __builtin_amdgcn_fdot2(__builtin_bit_cast(f16x2, xw),
                                  __builtin_bit_cast(f16x2, ww), acc, false);
#else
    f16x2 xv = __builtin_bit_cast(f16x2, xw);
    f16x2 wv = __builtin_bit_cast(f16x2, ww);
    return acc + (float)xv.x * (float)wv.x + (float)xv.y * (float)wv.y;
#endif
}

__device__ __forceinline__ uint32_t packf2(float a, float b) {
    f16x2 t;
    t.x = (_Float16)a;
    t.y = (_Float16)b;
    return __builtin_bit_cast(uint32_t, t);
}

__device__ __forceinline__ float sigm_(float z) {
    float e = __builtin_amdgcn_exp2f(-LOG2E * z);
    return __builtin_amdgcn_rcpf(1.0f + e);
}
__device__ __forceinline__ float tanh_(float z) {
    float e = __builtin_amdgcn_exp2f((2.0f * LOG2E) * z);
    float r = __builtin_amdgcn_rcpf(1.0f + e);
    return __builtin_fmaf(-2.0f, r, 1.0f);
}

// ====================== projection pass (unchanged, r9-validated) ======================
template <int DIN, int H, int NDIR, bool L1X>
__global__ void __launch_bounds__(256) proj_kernel(
    const float* __restrict__ x,        // L1X: [B][T][8] f32
    const __half* __restrict__ inbuf,   // else: [T][B][DIN] f16
    const float* __restrict__ w0,       // W_ih fwd [4H][DIN] f32
    const float* __restrict__ w1,       // W_ih bwd
    __half* __restrict__ g0,            // Gx fwd [seglen*B][4H] f16
    __half* __restrict__ g1,            // Gx bwd
    int t0, int seglen)
{
    constexpr int NDW  = DIN / 2;
    constexpr int XPAD = (NDW + 3) & ~3;
    constexpr int O4H  = 4 * H;
    constexpr int ODW  = O4H / 2;
    constexpr int RPB  = 16;
    constexpr int TPR  = 16;
    constexpr int OPT  = (O4H + TPR - 1) / TPR;
    constexpr int TILES = 8;

    __shared__ __align__(16) uint32_t wt[NDW][O4H];
    __shared__ __align__(16) uint32_t xin[RPB * XPAD];
    __shared__ __align__(16) uint32_t osm[RPB][ODW];

    const int tid  = threadIdx.x;
    const int dirz = (NDIR == 2) ? (int)blockIdx.y : 0;
    const float* w = dirz ? w1 : w0;
    __half* gout   = dirz ? g1 : g0;
    (void)seglen;

    for (int idx = tid; idx < NDW * O4H; idx += 256) {
        const int d  = idx / O4H;
        const int o  = idx - d * O4H;
        const int jj = o >> 2;
        const int qq = o & 3;
        wt[d][o] = packf2(w[(qq * H + jj) * DIN + 2 * d],
                          w[(qq * H + jj) * DIN + 2 * d + 1]);
    }
    __syncthreads();

    const int rr = tid >> 4;
    const int li = tid & 15;

    uint32_t wreg[NDW][OPT];
#pragma unroll
    for (int d = 0; d < NDW; ++d)
#pragma unroll
        for (int oi = 0; oi < OPT; ++oi) {
            const int o = li + oi * TPR;
            wreg[d][oi] = (O4H % TPR == 0 || o < O4H) ? wt[d][o] : 0u;
        }

    for (int tile = 0; tile < TILES; ++tile) {
        const int r0 = ((int)blockIdx.x * TILES + tile) * RPB;
        __syncthreads();

        for (int idx = tid; idx < RPB * NDW; idx += 256) {
            const int rl = idx / NDW;
            const int d  = idx - rl * NDW;
            const int r  = r0 + rl;
            const int i  = r >> 10;
            const int bb = r & (B_TOTAL - 1);
            const int t  = dirz ? (T_TOTAL - 1 - t0 - i) : (t0 + i);
            uint32_t v;
            if constexpr (L1X) {
                float2 u = {0.f, 0.f};
                if (d < 4)
                    u = ((const float2*)(x + ((size_t)bb * T_TOTAL + t) * 8))[d];
                else if (t > 0)
                    u = ((const float2*)(x + ((size_t)bb * T_TOTAL + (t - 1)) * 8))[d - 4];
                v = packf2(u.x, u.y);
            } else {
                v = ((const uint32_t*)inbuf)[((size_t)t * B_TOTAL + bb) * NDW + d];
            }
            xin[rl * XPAD + d] = v;
        }
        __syncthreads();

        float acc[OPT];
#pragma unroll
        for (int oi = 0; oi < OPT; ++oi) acc[oi] = 0.f;
        const uint32_t* xr = &xin[rr * XPAD];
#pragma unroll
        for (int d = 0; d + 4 <= NDW; d += 4) {
            const uint4 xv = *(const uint4*)(xr + d);
#pragma unroll
            for (int oi = 0; oi < OPT; ++oi) {
                acc[oi] = dot2w(xv.x, wreg[d][oi], acc[oi]);
                acc[oi] = dot2w(xv.y, wreg[d + 1][oi], acc[oi]);
                acc[oi] = dot2w(xv.z, wreg[d + 2][oi], acc[oi]);
                acc[oi] = dot2w(xv.w, wreg[d + 3][oi], acc[oi]);
            }
        }
        if constexpr ((NDW & 3) >= 2) {
            constexpr int d0 = NDW & ~3;
            const uint2 xv = *(const uint2*)(xr + d0);
#pragma unroll
            for (int oi = 0; oi < OPT; ++oi) {
                acc[oi] = dot2w(xv.x, wreg[d0][oi], acc[oi]);
                acc[oi] = dot2w(xv.y, wreg[d0 + 1][oi], acc[oi]);
            }
        }
        {
            __half* oh = (__half*)&osm[rr][0];
#pragma unroll
            for (int oi = 0; oi < OPT; ++oi) {
                const int o = li + oi * TPR;
                if (O4H % TPR == 0 || o < O4H) oh[o] = __float2half(acc[oi]);
            }
        }
        __syncthreads();

        {
            uint32_t* dst = (uint32_t*)gout;
            for (int idx = tid; idx < RPB * ODW; idx += 256) {
                const int r  = idx / ODW;
                const int od = idx - r * ODW;
                dst[(size_t)(r0 + r) * ODW + od] = osm[r][od];
            }
        }
    }
}

// ================== LDS-free scan (round 10) ==================
// r9 evidence: staged-LDS scan = 872 cy/step with 7.3M bank-conflict
// cycles; r7+r9 jointly show the scan is issue+DS-round-trip bound, not
// feed-bound. This version removes LDS from the scan entirely:
//  - h all-gather: v_mov_dpp pair-swap (VALU) + pack -> pair dword, then
//    NH ds_bpermute broadcasts (ONE DS latency, conflict-free) instead of
//    ds_write -> barrier -> ds_read (two serialized DS latencies).
//  - Gx feed: r6-proven global uint2 prefetch ring (L2/L3-resident).
//  - output: per-step 2B store (non-blocking, r6-proven).
// W_hh pinned in VGPRs via opaque asm (r0-r3 remat lesson).
template <int H, bool STORE_ALL>
__global__ void __launch_bounds__(64)
__attribute__((amdgpu_waves_per_eu(1, 1))) lstm_scan4(
    const __half* __restrict__ gxf, const __half* __restrict__ gxb,
    const float* __restrict__ whhf, const float* __restrict__ bihf,
    const float* __restrict__ bhhf,
    const float* __restrict__ whhb, const float* __restrict__ bihb,
    const float* __restrict__ bhhb,
    __half* __restrict__ outbuf,    // STORE_ALL: [T][B][2H] f16
    float* __restrict__ lasth,      // !STORE_ALL: [B][H] f32
    float* __restrict__ sth, float* __restrict__ stc,  // [2][B][H] f32 state
    int t0, int seglen)             // seglen multiple of 4 (>= 64)
{
    constexpr int GPW = 64 / H;
    constexpr int NH  = H / 2;
    constexpr int PF  = 4;

    const int dir  = blockIdx.y;
    const int lane = threadIdx.x;
    const int g    = lane / H;
    const int j    = lane - g * H;
    const int gs   = (g < GPW) ? g : (GPW - 1);
    const int b    = blockIdx.x * GPW + g;
    const bool valid = (g < GPW) && (b < B_TOTAL);
    const int bs   = valid ? b : (B_TOTAL - 1);

    const __half* gx  = dir ? gxb : gxf;
    const float* w_hh = dir ? whhb : whhf;
    const float* b_i  = dir ? bihb : bihf;
    const float* b_h  = dir ? bhhb : bhhf;

    // ---- W_hh + bias -> registers, pinned ----
    uint32_t whh2[4][NH];
    float bias[4];
#pragma unroll
    for (int q = 0; q < 4; ++q) {
        const int r = q * H + j;
#pragma unroll
        for (int k = 0; k < NH; ++k)
            whh2[q][k] = packf2(w_hh[r * H + 2 * k], w_hh[r * H + 2 * k + 1]);
        bias[q] = b_i[r] + b_h[r];
    }
#pragma unroll
    for (int q = 0; q < 4; ++q) {
#pragma unroll
        for (int k = 0; k < NH; ++k) asm volatile("" : "+v"(whh2[q][k]));
        asm volatile("" : "+v"(bias[q]));
    }

    // ---- h all-gather: DPP pair-swap + bpermute broadcasts ----
    const int  base4 = (gs * H) * 4;        // byte index of group's lane 0
    const bool evn   = ((lane & 1) == 0);
    uint32_t hd[NH];
    auto exchange = [&](float h) {
        const uint32_t hf = (uint32_t)__builtin_bit_cast(uint16_t, (_Float16)h);
        const uint32_t nb = (uint32_t)__builtin_amdgcn_mov_dpp(
            (int)hf, 0xB1 /*quad_perm [1,0,3,2]*/, 0xF, 0xF, true);
        const uint32_t lo = evn ? hf : nb;
        const uint32_t hi = evn ? nb : hf;
        const uint32_t pairw = lo | (hi << 16);
#pragma unroll
        for (int k = 0; k < NH; ++k)
            hd[k] = (uint32_t)__builtin_amdgcn_ds_bpermute(base4 + 8 * k, (int)pairw);
    };

    // ---- state (zeros at t0==0, else persisted) ----
    float c_st, h0;
    if (t0 == 0) {
        c_st = 0.f;
        h0   = 0.f;
    } else {
        h0   = sth[((size_t)dir * B_TOTAL + bs) * H + j];
        c_st = stc[((size_t)dir * B_TOTAL + bs) * H + j];
    }
    exchange(h0);

    // ---- Gx prefetch ring (rows are seg-local step indices) ----
    const size_t ISTR = (size_t)B_TOTAL * (4 * H) * 2;   // bytes per gx row
    const char*  gb   = (const char*)gx + ((size_t)bs * (4 * H) + (size_t)j * 4) * 2;

    uint2 pf[PF];
#pragma unroll
    for (int i2 = 0; i2 < PF; ++i2) {
        const int ip = (i2 < seglen) ? i2 : (seglen - 1);
        pf[i2] = *(const uint2*)(gb + (size_t)ip * ISTR);
    }

    __half* op = nullptr;
    ptrdiff_t opstep = 0;
    if constexpr (STORE_ALL) {
        const int tstart = dir ? (T_TOTAL - 1 - t0) : t0;
        op = outbuf + (size_t)tstart * (B_TOTAL * 2 * H) + (size_t)bs * (2 * H) + dir * H + j;
        opstep = (dir ? -1 : 1) * (ptrdiff_t)(B_TOTAL * 2 * H);
    }

    float hl = h0;

#define STEP(I)                                                               \
    {                                                                         \
        const uint2 gv = pf[I];                                               \
        int ip = sb + (I) + PF;                                               \
        ip = (ip < seglen) ? ip : (seglen - 1);                               \
        pf[I] = *(const uint2*)(gb + (size_t)ip * ISTR);                      \
        const f16x2 p01 = __builtin_bit_cast(f16x2, gv.x);                    \
        const f16x2 p23 = __builtin_bit_cast(f16x2, gv.y);                    \
        float a0 = (float)p01.x + bias[0];                                    \
        float a1 = (float)p01.y + bias[1];                                    \
        float a2 = (float)p23.x + bias[2];                                    \
        float a3 = (float)p23.y + bias[3];                                    \
        _Pragma("unroll")                                                     \
        for (int k = 0; k < NH; ++k) {                                        \
            a0 = dot2w(hd[k], whh2[0][k], a0);                                \
            a1 = dot2w(hd[k], whh2[1][k], a1);                                \
            a2 = dot2w(hd[k], whh2[2][k], a2);                                \
            a3 = dot2w(hd[k], whh2[3][k], a3);                                \
        }                                                                     \
        const float iv  = sigm_(a0);                                          \
        const float fv  = sigm_(a1);                                          \
        const float gg2 = tanh_(a2);                                          \
        const float ov  = sigm_(a3);                                          \
        c_st = __builtin_fmaf(fv, c_st, iv * gg2);                            \
        const float h = ov * tanh_(c_st);                                     \
        if constexpr (STORE_ALL) {                                            \
            if (valid) *op = __float2half(h);                                 \
            op += opstep;                                                     \
        }                                                                     \
        exchange(h);                                                          \
        hl = h;                                                               \
    }

    for (int sb = 0; sb < seglen; sb += PF) {
        STEP(0) STEP(1) STEP(2) STEP(3)
    }
#undef STEP

    if (valid) {
        sth[((size_t)dir * B_TOTAL + b) * H + j] = hl;
        stc[((size_t)dir * B_TOTAL + b) * H + j] = c_st;
        if constexpr (!STORE_ALL) lasth[b * H + j] = hl;
    }
}

// L4 backward needed only at t=T-1 (single step from zero state) + FC + sigmoid.
__global__ void final_kernel(const __half* __restrict__ l3out,  // [T][B][20] f16
                             const float* __restrict__ hf4,     // [B][10]
                             const float* __restrict__ w_ih,    // w4b_ih [40][20]
                             const float* __restrict__ b_ih,
                             const float* __restrict__ b_hh,
                             const float* __restrict__ fc_w,    // [20]
                             const float* __restrict__ fc_b,
                             float* __restrict__ out)           // [B]
{
    const int b = blockIdx.x * blockDim.x + threadIdx.x;
    if (b >= B_TOTAL) return;

    float in4[20];
    const __half* p = l3out + (size_t)(T_TOTAL - 1) * (B_TOTAL * 20) + (size_t)b * 20;
#pragma unroll
    for (int i = 0; i < 20; ++i) in4[i] = __half2float(p[i]);

    float z = fc_b[0];
#pragma unroll
    for (int k = 0; k < 10; ++k) z += fc_w[k] * hf4[b * 10 + k];

#pragma unroll
    for (int k = 0; k < 10; ++k) {
        float gi = b_ih[k]      + b_hh[k];
        float gg = b_ih[20 + k] + b_hh[20 + k];
        float go = b_ih[30 + k] + b_hh[30 + k];
#pragma unroll
        for (int i = 0; i < 20; ++i) {
            const float xi = in4[i];
            gi += w_ih[k * 20 + i]        * xi;
            gg += w_ih[(20 + k) * 20 + i] * xi;
            go += w_ih[(30 + k) * 20 + i] * xi;
        }
        const float cc = sigm_(gi) * tanh_(gg);
        const float hb = sigm_(go) * tanh_(cc);
        z += fc_w[10 + k] * hb;
    }
    out[b] = sigm_(z);
}

extern "C" void kernel_launch(void* const* d_in, const int* in_sizes, int n_in,
                              void* d_out, int out_size, void* d_ws, size_t ws_size,
                              hipStream_t stream) {
    const float* x = (const float*)d_in[0];
    auto W = [&](int li, int dr, int k) -> const float* {
        return (const float*)d_in[1 + (li - 1) * 8 + dr * 4 + k];
    };
    const float* fc_w = (const float*)d_in[33];
    const float* fc_b = (const float*)d_in[34];
    float* out = (float*)d_out;

    // ---- workspace layout (r6/r7/r9-validated) ----
    const size_t HA_B = (size_t)T_TOTAL * B_TOTAL * 40 * 2;
    const size_t HB_B = (size_t)T_TOTAL * B_TOTAL * 20 * 2;
    const size_t ST_B = 2ull * B_TOTAL * 20 * 4;
    const size_t F4_B = (size_t)B_TOTAL * 10 * 4;

    char* p = (char*)d_ws;
    __half* hA = (__half*)p;  p += HA_B;
    __half* hB = (__half*)p;  p += HB_B;
    float* sth = (float*)p;   p += ST_B;
    float* stc = (float*)p;   p += ST_B;
    float* hf4 = (float*)p;   p += F4_B;
    __half* gx = (__half*)p;

    const size_t base = HA_B + HB_B + 2 * ST_B + F4_B;
    int SEG = 64;
    if      (ws_size >= base + 1024ull * 327680) SEG = 1024;
    else if (ws_size >= base +  512ull * 327680) SEG = 512;
    else if (ws_size >= base +  256ull * 327680) SEG = 256;
    else if (ws_size >= base +  128ull * 327680) SEG = 128;
    const int nseg = T_TOTAL / SEG;

    auto g1of = [&](int H) { return gx + (size_t)SEG * 1024 * 4 * H; };

    // ---- L1: DIN=16 (x + lag), H=20 -> hA ----
    for (int s = 0; s < nseg; ++s) {
        proj_kernel<16, 20, 2, true><<<dim3(SEG * 8, 2), 256, 0, stream>>>(
            x, nullptr, W(1,0,0), W(1,1,0), gx, g1of(20), s * SEG, SEG);
        lstm_scan4<20, true><<<dim3(342, 2), 64, 0, stream>>>(
            gx, g1of(20), W(1,0,1), W(1,0,2), W(1,0,3),
                          W(1,1,1), W(1,1,2), W(1,1,3),
            hA, nullptr, sth, stc, s * SEG, SEG);
    }
    // ---- L2: DIN=40, H=20, hA -> hA (in-place; proj(s) precedes scan(s)) ----
    for (int s = 0; s < nseg; ++s) {
        proj_kernel<40, 20, 2, false><<<dim3(SEG * 8, 2), 256, 0, stream>>>(
            nullptr, hA, W(2,0,0), W(2,1,0), gx, g1of(20), s * SEG, SEG);
        lstm_scan4<20, true><<<dim3(342, 2), 64, 0, stream>>>(
            gx, g1of(20), W(2,0,1), W(2,0,2), W(2,0,3),
                          W(2,1,1), W(2,1,2), W(2,1,3),
            hA, nullptr, sth, stc, s * SEG, SEG);
    }
    // ---- L3: DIN=40, H=10, hA -> hB ----
    for (int s = 0; s < nseg; ++s) {
        proj_kernel<40, 10, 2, false><<<dim3(SEG * 8, 2), 256, 0, stream>>>(
            nullptr, hA, W(3,0,0), W(3,1,0), gx, g1of(10), s * SEG, SEG);
        lstm_scan4<10, true><<<dim3(171, 2), 64, 0, stream>>>(
            gx, g1of(10), W(3,0,1), W(3,0,2), W(3,0,3),
                          W(3,1,1), W(3,1,2), W(3,1,3),
            hB, nullptr, sth, stc, s * SEG, SEG);
    }
    // ---- L4 forward only: DIN=20, H=10, hB -> hf4 ----
    for (int s = 0; s < nseg; ++s) {
        proj_kernel<20, 10, 1, false><<<dim3(SEG * 8, 1), 256, 0, stream>>>(
            nullptr, hB, W(4,0,0), W(4,0,0), gx, gx, s * SEG, SEG);
        lstm_scan4<10, false><<<dim3(171, 1), 64, 0, stream>>>(
            gx, gx, W(4,0,1), W(4,0,2), W(4,0,3),
                    W(4,0,1), W(4,0,2), W(4,0,3),
            nullptr, hf4, sth, stc, s * SEG, SEG);
    }

    final_kernel<<<dim3(4), 256, 0, stream>>>(
        hB, hf4, W(4,1,0), W(4,1,2), W(4,1,3), fc_w, fc_b, out);
}